// Round 4
// baseline (307.241 us; speedup 1.0000x reference)
//
#include <hip/hip_runtime.h>

#define N_NODES 10000
#define N_EDGES 320000
#define DIM_IN  256
#define DD      128
#define HH      4
#define HD      512
#define GG      64

// ---------------- CSR build ----------------
__global__ void hist_kernel(const int* __restrict__ dst, int* __restrict__ cnt) {
  int e = blockIdx.x * 256 + threadIdx.x;
  atomicAdd(&cnt[dst[e]], 1);
}

__global__ void scan_kernel(const int* __restrict__ cnt, int* __restrict__ row_off) {
  __shared__ int part[1024];
  int t = threadIdx.x;
  int base = t * 10;
  int s = 0;
#pragma unroll
  for (int i = 0; i < 10; i++) { int idx = base + i; if (idx < N_NODES) s += cnt[idx]; }
  part[t] = s;
  __syncthreads();
  for (int off = 1; off < 1024; off <<= 1) {
    int v = (t >= off) ? part[t - off] : 0;
    __syncthreads();
    part[t] += v;
    __syncthreads();
  }
  int run = part[t] - s;
  for (int i = 0; i < 10; i++) {
    int idx = base + i;
    if (idx < N_NODES) { row_off[idx] = run; run += cnt[idx]; }
  }
  if (t == 1023) row_off[N_NODES] = part[1023];
}

__global__ void scatter_kernel(const int* __restrict__ src, const int* __restrict__ dst,
                               const int* __restrict__ row_off,
                               int* __restrict__ fill, int* __restrict__ srcl) {
  int e = blockIdx.x * 256 + threadIdx.x;
  int d = dst[e];
  int pos = row_off[d] + atomicAdd(&fill[d], 1);
  srcl[pos] = src[e];
}

// ---------------- dual GEMM: C1 = A@B1+bias1, C2 = A@B2+bias2 ----------------
// A-tile stored k-major (transposed) in LDS; BN fixed at 64.
template <int K, int NCOL, int BM>
__global__ __launch_bounds__(256) void dual_gemm(
    const float* __restrict__ A,
    const float* __restrict__ B1, const float* __restrict__ bias1,
    const float* __restrict__ B2, const float* __restrict__ bias2,
    float* __restrict__ C1, float* __restrict__ C2, int M) {
  constexpr int MR = BM / 16;                 // rows per thread (8 or 2)
  constexpr int NQ = (BM * 4 + 255) / 256;    // A-quarters per thread
  __shared__ float At[16][BM + 4];
  __shared__ float Bs[16][68];
  __shared__ float Bd[16][68];
  int t = threadIdx.x;
  int col0 = blockIdx.x * 64;
  int row0 = blockIdx.y * BM;
  int bk = t >> 4, bc = (t & 15) * 4;
  int tx = t & 15, ty = t >> 4;
  float acc1[MR][4] = {}, acc2[MR][4] = {};
  for (int k0 = 0; k0 < K; k0 += 16) {
    float4 aq[NQ];
#pragma unroll
    for (int qi = 0; qi < NQ; qi++) {
      int q = t + qi * 256;
      if (q < BM * 4) {
        int row = q >> 2, kc = (q & 3) * 4;
        aq[qi] = (row0 + row < M)
                     ? *(const float4*)(A + (size_t)(row0 + row) * K + k0 + kc)
                     : make_float4(0.f, 0.f, 0.f, 0.f);
      }
    }
    float4 b1v = *(const float4*)(B1 + (size_t)(k0 + bk) * NCOL + col0 + bc);
    float4 b2v = *(const float4*)(B2 + (size_t)(k0 + bk) * NCOL + col0 + bc);
    __syncthreads();
#pragma unroll
    for (int qi = 0; qi < NQ; qi++) {
      int q = t + qi * 256;
      if (q < BM * 4) {
        int row = q >> 2, kc = (q & 3) * 4;
        At[kc + 0][row] = aq[qi].x;
        At[kc + 1][row] = aq[qi].y;
        At[kc + 2][row] = aq[qi].z;
        At[kc + 3][row] = aq[qi].w;
      }
    }
    *(float4*)&Bs[bk][bc] = b1v;
    *(float4*)&Bd[bk][bc] = b2v;
    __syncthreads();
#pragma unroll
    for (int kk = 0; kk < 16; kk++) {
      float a[MR];
      if constexpr (MR == 8) {
        float4 x0 = *(const float4*)&At[kk][ty * 8];
        float4 x1 = *(const float4*)&At[kk][ty * 8 + 4];
        a[0] = x0.x; a[1] = x0.y; a[2] = x0.z; a[3] = x0.w;
        a[4] = x1.x; a[5] = x1.y; a[6] = x1.z; a[7] = x1.w;
      } else {
        float2 x0 = *(const float2*)&At[kk][ty * 2];
        a[0] = x0.x; a[1] = x0.y;
      }
      float4 br1 = *(const float4*)&Bs[kk][tx * 4];
      float4 br2 = *(const float4*)&Bd[kk][tx * 4];
      float b1r[4] = {br1.x, br1.y, br1.z, br1.w};
      float b2r[4] = {br2.x, br2.y, br2.z, br2.w};
#pragma unroll
      for (int i = 0; i < MR; i++)
#pragma unroll
        for (int j = 0; j < 4; j++) {
          acc1[i][j] = fmaf(a[i], b1r[j], acc1[i][j]);
          acc2[i][j] = fmaf(a[i], b2r[j], acc2[i][j]);
        }
    }
  }
#pragma unroll
  for (int i = 0; i < MR; i++) {
    int row = row0 + ty * MR + i;
    if (row < M) {
      float4 o1, o2;
      int cb = col0 + tx * 4;
      o1.x = acc1[i][0] + bias1[cb + 0]; o1.y = acc1[i][1] + bias1[cb + 1];
      o1.z = acc1[i][2] + bias1[cb + 2]; o1.w = acc1[i][3] + bias1[cb + 3];
      o2.x = acc2[i][0] + bias2[cb + 0]; o2.y = acc2[i][1] + bias2[cb + 1];
      o2.z = acc2[i][2] + bias2[cb + 2]; o2.w = acc2[i][3] + bias2[cb + 3];
      *(float4*)(C1 + (size_t)row * NCOL + cb) = o1;
      *(float4*)(C2 + (size_t)row * NCOL + cb) = o2;
    }
  }
}

// ---------------- layer 1 fused: wave per node, no LDS, no syncs ----------------
__global__ __launch_bounds__(256) void fused_gat1(
    const float* __restrict__ hs, const float* __restrict__ hd,
    const float* __restrict__ attn, const int* __restrict__ row_off,
    const int* __restrict__ srcl, float* __restrict__ out) {
  int t = threadIdx.x;
  int w = t >> 6, lane = t & 63;
  int v = blockIdx.x * 4 + w;
  int start = row_off[v];
  int deg = row_off[v + 1] - start;

  const float* ap = attn + lane * 8;
  const float* hp = hd + (size_t)v * HD + lane * 8;
  float4 a0 = *(const float4*)ap, a1 = *(const float4*)(ap + 4);
  float4 g0 = *(const float4*)hp, g1 = *(const float4*)(hp + 4);
  float areg[8] = {a0.x, a0.y, a0.z, a0.w, a1.x, a1.y, a1.z, a1.w};
  float hdreg[8] = {g0.x, g0.y, g0.z, g0.w, g1.x, g1.y, g1.z, g1.w};
  const float* hsl = hs + lane * 8;

  float ssum = 0.f;
  float acc[8] = {0.f, 0.f, 0.f, 0.f, 0.f, 0.f, 0.f, 0.f};

  int i = 0;
  float4 p00 = {0,0,0,0}, p01 = {0,0,0,0}, p10 = {0,0,0,0}, p11 = {0,0,0,0};
  bool h0 = 0 < deg, h1 = 1 < deg;
  if (h0) { const float* p = hsl + (size_t)srcl[start] * HD; p00 = *(const float4*)p; p01 = *(const float4*)(p + 4); }
  if (h1) { const float* p = hsl + (size_t)srcl[start + 1] * HD; p10 = *(const float4*)p; p11 = *(const float4*)(p + 4); }
  while (h0) {
    float hv0[8] = {p00.x, p00.y, p00.z, p00.w, p01.x, p01.y, p01.z, p01.w};
    float hv1[8] = {p10.x, p10.y, p10.z, p10.w, p11.x, p11.y, p11.z, p11.w};
    bool h1c = h1;
    int inx = i + 2;
    h0 = inx < deg; h1 = inx + 1 < deg;
    if (h0) { const float* p = hsl + (size_t)srcl[start + inx] * HD; p00 = *(const float4*)p; p01 = *(const float4*)(p + 4); }
    if (h1) { const float* p = hsl + (size_t)srcl[start + inx + 1] * HD; p10 = *(const float4*)p; p11 = *(const float4*)(p + 4); }
    float part0 = 0.f, part1 = 0.f;
#pragma unroll
    for (int j = 0; j < 8; j++) {
      float u0 = hv0[j] + hdreg[j];
      u0 = fmaxf(u0, 0.2f * u0);
      part0 = fmaf(u0, areg[j], part0);
      float u1 = hv1[j] + hdreg[j];
      u1 = fmaxf(u1, 0.2f * u1);
      part1 = fmaf(u1, areg[j], part1);
    }
#pragma unroll
    for (int k = 1; k < 16; k <<= 1) {
      part0 += __shfl_xor(part0, k);
      part1 += __shfl_xor(part1, k);
    }
    float wg0 = __expf(part0);
    float wg1 = h1c ? __expf(part1) : 0.f;
    ssum += wg0 + wg1;
#pragma unroll
    for (int j = 0; j < 8; j++)
      acc[j] = fmaf(wg0, hv0[j], fmaf(wg1, hv1[j], acc[j]));
    i = inx;
  }
  float inv = ssum > 0.f ? 1.f / ssum : 0.f;
  float* op = out + (size_t)v * HD + lane * 8;
  *(float4*)op = make_float4(acc[0] * inv, acc[1] * inv, acc[2] * inv, acc[3] * inv);
  *(float4*)(op + 4) = make_float4(acc[4] * inv, acc[5] * inv, acc[6] * inv, acc[7] * inv);
}

// ---------------- layer 2 fused: wave per node, 4 x 16-lane edge groups --------
__global__ __launch_bounds__(256) void fused_gat2(
    const float* __restrict__ hs, const float* __restrict__ hd,
    const float* __restrict__ attn, const int* __restrict__ row_off,
    const int* __restrict__ srcl, float* __restrict__ out) {
  int t = threadIdx.x;
  int w = t >> 6, lane = t & 63, grp = lane >> 4, sl = lane & 15;
  int v = blockIdx.x * 4 + w;
  int start = row_off[v];
  int deg = row_off[v + 1] - start;

  const float* ap = attn + sl * 8;
  const float* hp = hd + (size_t)v * DD + sl * 8;
  float4 a0 = *(const float4*)ap, a1 = *(const float4*)(ap + 4);
  float4 g0 = *(const float4*)hp, g1 = *(const float4*)(hp + 4);
  float areg[8] = {a0.x, a0.y, a0.z, a0.w, a1.x, a1.y, a1.z, a1.w};
  float hdreg[8] = {g0.x, g0.y, g0.z, g0.w, g1.x, g1.y, g1.z, g1.w};
  const float* hsl = hs + sl * 8;

  float ssum = 0.f;
  float acc[8] = {0.f, 0.f, 0.f, 0.f, 0.f, 0.f, 0.f, 0.f};

  int i = grp;
  float4 c0 = {0,0,0,0}, c1 = {0,0,0,0};
  bool has = i < deg;
  if (has) { const float* p = hsl + (size_t)srcl[start + i] * DD; c0 = *(const float4*)p; c1 = *(const float4*)(p + 4); }
  while (has) {
    float hv[8] = {c0.x, c0.y, c0.z, c0.w, c1.x, c1.y, c1.z, c1.w};
    int inx = i + 4;
    has = inx < deg;
    if (has) { const float* p = hsl + (size_t)srcl[start + inx] * DD; c0 = *(const float4*)p; c1 = *(const float4*)(p + 4); }
    float part = 0.f;
#pragma unroll
    for (int j = 0; j < 8; j++) {
      float u = hv[j] + hdreg[j];
      u = fmaxf(u, 0.2f * u);
      part = fmaf(u, areg[j], part);
    }
#pragma unroll
    for (int k = 1; k < 16; k <<= 1) part += __shfl_xor(part, k);
    float wg = __expf(part);
    ssum += wg;
#pragma unroll
    for (int j = 0; j < 8; j++) acc[j] = fmaf(wg, hv[j], acc[j]);
    i = inx;
  }
  // merge 4 groups within the wave
#pragma unroll
  for (int j = 0; j < 8; j++) {
    acc[j] += __shfl_xor(acc[j], 16);
    acc[j] += __shfl_xor(acc[j], 32);
  }
  ssum += __shfl_xor(ssum, 16);
  ssum += __shfl_xor(ssum, 32);
  float inv = ssum > 0.f ? 1.f / ssum : 0.f;
  if (lane < 16) {
    float* op = out + (size_t)v * DD + sl * 8;
    *(float4*)op = make_float4(acc[0] * inv, acc[1] * inv, acc[2] * inv, acc[3] * inv);
    *(float4*)(op + 4) = make_float4(acc[4] * inv, acc[5] * inv, acc[6] * inv, acc[7] * inv);
  }
}

// ---------------- pooling (binary search on sorted gid) + readout MLP ----------
__global__ __launch_bounds__(128) void final_kernel(
    const float* __restrict__ h2, const int* __restrict__ gid,
    const float* __restrict__ Wr1, const float* __restrict__ br1,
    const float* __restrict__ Wr2, const float* __restrict__ br2,
    float* __restrict__ out) {
  int g = blockIdx.x, t = threadIdx.x;
  int a, b;
  { int l = 0, h = N_NODES; while (l < h) { int m = (l + h) >> 1; if (gid[m] < g) l = m + 1; else h = m; } a = l; }
  { int l = a, h = N_NODES; while (l < h) { int m = (l + h) >> 1; if (gid[m] < g + 1) l = m + 1; else h = m; } b = l; }
  float s0 = 0.f, s1 = 0.f, s2 = 0.f, s3 = 0.f;
  int v = a;
  for (; v + 3 < b; v += 4) {
    s0 += h2[(size_t)(v + 0) * DD + t];
    s1 += h2[(size_t)(v + 1) * DD + t];
    s2 += h2[(size_t)(v + 2) * DD + t];
    s3 += h2[(size_t)(v + 3) * DD + t];
  }
  for (; v < b; v++) s0 += h2[(size_t)v * DD + t];
  __shared__ float hgn[128];
  float cnt = (float)(b - a);
  hgn[t] = ((s0 + s1) + (s2 + s3)) / fmaxf(cnt, 1.f);
  __syncthreads();
  if (t < 64) {
    float r = br1[t];
#pragma unroll 8
    for (int k = 0; k < 128; k++) r = fmaf(hgn[k], Wr1[k * 64 + t], r);
    r = fmaxf(r, 0.f);
    float p = r * Wr2[t];
#pragma unroll
    for (int k = 1; k < 64; k <<= 1) p += __shfl_xor(p, k);
    if (t == 0) out[g] = p + br2[0];
  }
}

extern "C" void kernel_launch(void* const* d_in, const int* in_sizes, int n_in,
                              void* d_out, int out_size, void* d_ws, size_t ws_size,
                              hipStream_t stream) {
  (void)in_sizes; (void)n_in; (void)out_size; (void)ws_size;
  const float* x     = (const float*)d_in[0];
  const float* W1s   = (const float*)d_in[1];
  const float* b1s   = (const float*)d_in[2];
  const float* W1d   = (const float*)d_in[3];
  const float* b1d   = (const float*)d_in[4];
  const float* attn1 = (const float*)d_in[5];
  const float* W2s   = (const float*)d_in[6];
  const float* b2s   = (const float*)d_in[7];
  const float* W2d   = (const float*)d_in[8];
  const float* b2d   = (const float*)d_in[9];
  const float* attn2 = (const float*)d_in[10];
  const float* Wr1   = (const float*)d_in[11];
  const float* br1   = (const float*)d_in[12];
  const float* Wr2   = (const float*)d_in[13];
  const float* br2   = (const float*)d_in[14];
  const int* src     = (const int*)d_in[15];
  const int* dst     = (const int*)d_in[16];
  const int* gid     = (const int*)d_in[17];
  float* out = (float*)d_out;

  char* ws = (char*)d_ws;
  float* hs1     = (float*)(ws + 0);          // N*512 f32
  float* hd1     = (float*)(ws + 20480000);   // N*512 f32
  float* h1      = (float*)(ws + 40960000);   // N*512 f32
  int*   srcl    = (int*)(ws + 61440000);     // E int
  int*   row_off = (int*)(ws + 62720000);     // (N+1) int
  int*   cnt     = (int*)(ws + 62760448);     // N int
  int*   fill    = (int*)(ws + 62800448);     // N int (contiguous with cnt)
  float* hs2 = hs1;
  float* hd2 = hd1;
  float* h2  = h1;

  hipMemsetAsync(cnt, 0, 2 * N_NODES * 4, stream);

  hist_kernel<<<N_EDGES / 256, 256, 0, stream>>>(dst, cnt);
  scan_kernel<<<1, 1024, 0, stream>>>(cnt, row_off);
  scatter_kernel<<<N_EDGES / 256, 256, 0, stream>>>(src, dst, row_off, fill, srcl);

  dual_gemm<DIM_IN, HD, 128><<<dim3(HD / 64, (N_NODES + 127) / 128), 256, 0, stream>>>(
      x, W1s, b1s, W1d, b1d, hs1, hd1, N_NODES);
  fused_gat1<<<(N_NODES + 3) / 4, 256, 0, stream>>>(hs1, hd1, attn1, row_off, srcl, h1);

  dual_gemm<HD, DD, 32><<<dim3(DD / 64, (N_NODES + 31) / 32), 256, 0, stream>>>(
      h1, W2s, b2s, W2d, b2d, hs2, hd2, N_NODES);
  fused_gat2<<<(N_NODES + 3) / 4, 256, 0, stream>>>(hs2, hd2, attn2, row_off, srcl, h2);

  final_kernel<<<GG, 128, 0, stream>>>(h2, gid, Wr1, br1, Wr2, br2, out);
}